// Round 6
// baseline (477.380 us; speedup 1.0000x reference)
//
#include <hip/hip_runtime.h>
#include <hip/hip_bf16.h>

#define B_ 2
#define C_ 256
#define NH_ 8
#define D_ 32
#define N_ 4096
#define NHALF_ 2048
#define SCALE_ 0.17677669529663689f
// SCALE * log2(e): folded into Q so softmax is a bare v_exp_f32 per score
#define QSC_ 0.25505277f

typedef __hip_bfloat16 bf16;
typedef __attribute__((ext_vector_type(8))) short sx8;   // 8 bf16 = one MFMA A/B frag
typedef __attribute__((ext_vector_type(4))) short sx4;
typedef __attribute__((ext_vector_type(4))) float fx4;   // MFMA C/D frag
typedef __attribute__((ext_vector_type(4))) int ix4;

__device__ __forceinline__ float b2f(bf16 x) { return __bfloat162float(x); }
__device__ __forceinline__ bf16 f2b(float x) { return __float2bfloat16(x); }
__device__ __forceinline__ short fbs(float x) { bf16 h = __float2bfloat16(x); return *(short*)&h; }
__device__ __forceinline__ float sbf(short s) { bf16 h = *(bf16*)&s; return __bfloat162float(h); }

#if __has_builtin(__builtin_amdgcn_exp2f)
__device__ __forceinline__ float fexp2(float x) { return __builtin_amdgcn_exp2f(x); }
#else
__device__ __forceinline__ float fexp2(float x) { return exp2f(x); }
#endif

// pack two f32 -> one dword of two bf16 by TRUNCATION (1 VALU op via v_perm).
// P in (0,1]; l sums the same truncated values so normalization cancels bias.
__device__ __forceinline__ unsigned pkbf_tr(float x, float y) {
#if __has_builtin(__builtin_amdgcn_perm)
  return __builtin_amdgcn_perm(__builtin_bit_cast(unsigned, y),
                               __builtin_bit_cast(unsigned, x), 0x07060302u);
#else
  unsigned a = __builtin_bit_cast(unsigned, x) >> 16;
  unsigned b = __builtin_bit_cast(unsigned, y) & 0xFFFF0000u;
  return a | b;
#endif
}
// gfx950 MFMA-transpose swaps (VALU cross-lane, not DS pipe) — validated R10.
// VOLATILE on purpose (R17 lesson: removing the fences lets the scheduler
// sink prefetch loads and destroy the software pipeline).
__device__ __forceinline__ void pl32swap(unsigned &a, unsigned &b) {
  asm volatile("v_permlane32_swap_b32 %0, %1" : "+v"(a), "+v"(b));
}
__device__ __forceinline__ void pl16swap(unsigned &a, unsigned &b) {
  asm volatile("v_permlane16_swap_b32 %0, %1" : "+v"(a), "+v"(b));
}

// ---------------------------------------------------------------------------
// Prep (merged): z<4 -> x transpose+convert to xb[z][p][c];
//                z==4 -> weights -> bf16 (wb stacked [wq;wk;wv], wob).
// grid (N_/64, C_/64, 5), block 256
// ---------------------------------------------------------------------------
__global__ __launch_bounds__(256)
void convert_kernel(const float* __restrict__ spatial,
                    const float* __restrict__ freq,
                    const float* __restrict__ wq, const float* __restrict__ wk,
                    const float* __restrict__ wv, const float* __restrict__ wo,
                    bf16* __restrict__ xb, bf16* __restrict__ wb,
                    bf16* __restrict__ wob) {
  const int tid = threadIdx.x;
  if (blockIdx.z == 4) {
    int base = (blockIdx.y * 64 + blockIdx.x) * 256 + tid;   // 0..65535
    #pragma unroll
    for (int i = 0; i < 4; ++i) {
      int idx = base + i * 65536;                            // 0..262143
      if (idx < 196608) {
        const float* src = (idx < 65536) ? wq : (idx < 131072) ? wk : wv;
        wb[idx] = f2b(src[idx & 65535]);
      } else {
        wob[idx - 196608] = f2b(wo[idx - 196608]);
      }
    }
    return;
  }

  const int p0 = blockIdx.x * 64;
  const int c0 = blockIdx.y * 64;
  const int z  = blockIdx.z;            // s*B_ + b
  const int s = z >> 1, b = z & 1;
  const float* x = (s == 0) ? spatial : freq;

  __shared__ float ls[64][65];

  const int pp = tid & 63, cb = tid >> 6;
  #pragma unroll
  for (int i = 0; i < 16; ++i) {
    int c = cb + 4 * i;
    ls[c][pp] = x[(size_t)(b * C_ + c0 + c) * N_ + p0 + pp];
  }
  __syncthreads();

  #pragma unroll
  for (int i = 0; i < 2; ++i) {
    int j = tid + 256 * i;              // 0..511
    int p = j >> 3, ck = (j & 7) * 8;
    short tmp[8];
    #pragma unroll
    for (int u = 0; u < 8; ++u) tmp[u] = fbs(ls[ck + u][p]);
    *(sx8*)(xb + ((size_t)z * N_ + p0 + p) * C_ + c0 + ck) = *(sx8*)tmp;
  }
}

// ---------------------------------------------------------------------------
// Kernel 1: QKV projection as MFMA GEMM. D = W (768x256) * x (256x4096) per z.
//   qhf/khf: per-head pos-major [z][h][n][d32]   (Q pre-scaled by QSC_)
//   vhf:     frag-blocked [z][h][n>>5][d>>4][d&15][n&31]
// grid (N_/128, 768/128, 2*B_), block 256 (4 waves, each 64x64)
// ---------------------------------------------------------------------------
__global__ __launch_bounds__(256)
void qkv_gemm_kernel(const bf16* __restrict__ wb, const bf16* __restrict__ xb,
                     const float* __restrict__ bq, const float* __restrict__ bk,
                     const float* __restrict__ bv,
                     bf16* __restrict__ qhf, bf16* __restrict__ khf,
                     bf16* __restrict__ vhf) {
  const int tid = threadIdx.x;
  const int p0 = blockIdx.x * 128;
  const int o0 = blockIdx.y * 128;
  const int z  = blockIdx.z;

  const int lane = tid & 63, w = tid >> 6;
  const int ml = lane & 15, Q4 = (lane >> 4) * 4, Q8 = (lane >> 4) * 8;
  const int ow = (w >> 1) * 64, pw = (w & 1) * 64;

  __shared__ __align__(16) short asb[128 * 72];
  __shared__ __align__(16) short bsb[128 * 72];
  __shared__ float bias_s[128];

  if (tid < 128) {
    int o = o0 + tid;
    bias_s[tid] = (o < 256) ? bq[o] : (o < 512) ? bk[o - 256] : bv[o - 512];
  }

  const fx4 z4 = {0.f, 0.f, 0.f, 0.f};
  fx4 acc[4][4];
  #pragma unroll
  for (int ot = 0; ot < 4; ++ot)
    #pragma unroll
    for (int pt = 0; pt < 4; ++pt) acc[ot][pt] = z4;

  const int sr = tid >> 1, scu = (tid & 1) * 32;
  for (int k0 = 0; k0 < 256; k0 += 64) {
    __syncthreads();
    #pragma unroll
    for (int u = 0; u < 4; ++u) {
      *(sx8*)&asb[sr * 72 + scu + u * 8] =
          *(const sx8*)&wb[(o0 + sr) * 256 + k0 + scu + u * 8];
      *(sx8*)&bsb[sr * 72 + scu + u * 8] =
          *(const sx8*)(xb + ((size_t)z * N_ + p0 + sr) * C_ + k0 + scu + u * 8);
    }
    __syncthreads();
    #pragma unroll
    for (int kk = 0; kk < 2; ++kk) {
      sx8 af[4], bfr[4];
      #pragma unroll
      for (int t = 0; t < 4; ++t)
        af[t] = *(sx8*)&asb[(ow + t * 16 + ml) * 72 + kk * 32 + Q8];
      #pragma unroll
      for (int t = 0; t < 4; ++t)
        bfr[t] = *(sx8*)&bsb[(pw + t * 16 + ml) * 72 + kk * 32 + Q8];
      #pragma unroll
      for (int ot = 0; ot < 4; ++ot)
        #pragma unroll
        for (int pt = 0; pt < 4; ++pt)
          acc[ot][pt] = __builtin_amdgcn_mfma_f32_16x16x32_bf16(
              af[ot], bfr[pt], acc[ot][pt], 0, 0, 0);
    }
  }

  if (o0 < 512) {
    bf16* dst = (o0 < 256) ? qhf : khf;
    const int ob = (o0 < 256) ? o0 : o0 - 256;
    const float scl = (o0 < 256) ? QSC_ : 1.f;
    #pragma unroll
    for (int ot = 0; ot < 4; ++ot) {
      const int og = ob + ow + ot * 16 + Q4;    // global o, head = og>>5
      #pragma unroll
      for (int pt = 0; pt < 4; ++pt) {
        int p = p0 + pw + pt * 16 + ml;
        short tmp[4];
        #pragma unroll
        for (int r = 0; r < 4; ++r)
          tmp[r] = fbs((acc[ot][pt][r] + bias_s[ow + ot * 16 + Q4 + r]) * scl);
        *(sx4*)(dst + (((size_t)z * NH_ + (og >> 5)) * N_ + p) * D_ + (og & 31)) =
            *(sx4*)tmp;
      }
    }
  } else {
    #pragma unroll
    for (int ot = 0; ot < 4; ++ot)
      #pragma unroll
      for (int pt = 0; pt < 4; ++pt) {
        int p = p0 + pw + pt * 16 + ml;
        #pragma unroll
        for (int r = 0; r < 4; ++r) {
          int lo = ow + ot * 16 + Q4 + r;       // local o in [0,128)
          int rho = (o0 - 512) + lo;            // 0..255
          int h = rho >> 5, d = rho & 31;
          size_t basev = ((size_t)z * NH_ + h) * D_ * N_;
          vhf[basev + (size_t)(((p >> 5) * 2) + (d >> 4)) * 512 +
              (d & 15) * 32 + (p & 31)] = f2b(acc[ot][pt][r] + bias_s[lo]);
        }
      }
  }
}

// ---------------------------------------------------------------------------
// Kernel 2: MFMA flash attention, R20 — SPLIT-K over the key axis.
// R15 anchor (98.4us): MfmaUtil 36.4 + pure-VALU ~25 + ~38% STALL (corrected
// counter model: VALUBusy includes MFMA). R16 showed more waves at HALVED
// per-wave intensity regress; R17/R18 showed scheduling can't remove the
// stall. Split-K is the untried lever: each block runs the EXACT R15 inner
// loop (same 64q x 64-key tiles, same intensity) over HALF the keys ->
// 1024 blocks = 4 blocks/CU = 4 waves/SIMD at proven per-tile efficiency,
// multiplexing away the latency stall. Epilogue stores UNNORMALIZED O (bf16)
// + l (f32); out_proj combines the halves.
// grid (N_/256, NH_, 2*B_*2), block 256; VGPR 92 fits 4 waves/SIMD.
// ---------------------------------------------------------------------------
__device__ __forceinline__ void attn_tile(const sx8 kf[4], const sx8 vf[2][2],
                                          const sx8 qf[4], sx8 onesf,
                                          fx4 acc[4][2], fx4 lacc[4]) {
  const fx4 z4 = {0.f, 0.f, 0.f, 0.f};
  #pragma unroll
  for (int s4 = 0; s4 < 4; ++s4) {
    fx4 st[4];
    __builtin_amdgcn_s_setprio(1);
    #pragma unroll
    for (int t = 0; t < 4; ++t)
      st[t] = __builtin_amdgcn_mfma_f32_16x16x32_bf16(kf[t], qf[s4], z4, 0, 0, 0);
    __builtin_amdgcn_s_setprio(0);

    // exp + truncate-pack each tile's 4 values into 2 dwords
    unsigned T[4][2];
    #pragma unroll
    for (int t = 0; t < 4; ++t) {
      float e0 = fexp2(st[t][0]), e1 = fexp2(st[t][1]);
      float e2 = fexp2(st[t][2]), e3 = fexp2(st[t][3]);
      T[t][0] = pkbf_tr(e0, e1);
      T[t][1] = pkbf_tr(e2, e3);
    }
    // in-register C-layout -> B-operand transform (validated R10)
    pl32swap(T[0][0], T[1][0]); pl16swap(T[0][0], T[1][0]);
    pl32swap(T[0][1], T[1][1]); pl16swap(T[0][1], T[1][1]);
    pl32swap(T[2][0], T[3][0]); pl16swap(T[2][0], T[3][0]);
    pl32swap(T[2][1], T[3][1]); pl16swap(T[2][1], T[3][1]);
    ix4 p0 = {(int)T[0][0], (int)T[0][1], (int)T[1][0], (int)T[1][1]};
    ix4 p1 = {(int)T[2][0], (int)T[2][1], (int)T[3][0], (int)T[3][1]};
    sx8 pf0 = *(sx8*)&p0;
    sx8 pf1 = *(sx8*)&p1;

    __builtin_amdgcn_s_setprio(1);
    lacc[s4] = __builtin_amdgcn_mfma_f32_16x16x32_bf16(onesf, pf0, lacc[s4], 0, 0, 0);
    lacc[s4] = __builtin_amdgcn_mfma_f32_16x16x32_bf16(onesf, pf1, lacc[s4], 0, 0, 0);
    #pragma unroll
    for (int dt = 0; dt < 2; ++dt) {
      fx4 a = acc[s4][dt];
      a = __builtin_amdgcn_mfma_f32_16x16x32_bf16(vf[dt][0], pf0, a, 0, 0, 0);
      a = __builtin_amdgcn_mfma_f32_16x16x32_bf16(vf[dt][1], pf1, a, 0, 0, 0);
      acc[s4][dt] = a;
    }
    __builtin_amdgcn_s_setprio(0);
  }
}

__global__ __launch_bounds__(256, 4)
void attn_kernel(const bf16* __restrict__ qhf, const bf16* __restrict__ khf,
                 const bf16* __restrict__ vhf, bf16* __restrict__ attoT,
                 float* __restrict__ lws) {
  const int tid  = threadIdx.x;
  const int m0   = blockIdx.x * 256;
  const int h    = blockIdx.y;
  const int zz   = blockIdx.z;          // z*2 + half
  const int z    = zz >> 1, half = zz & 1;
  const int s = z >> 1, b = z & 1;
  const int zo = ((1 - s) << 1) | b;    // kv source

  const bf16* qz = qhf + ((size_t)z  * NH_ + h) * N_ * D_;
  const bf16* kz = khf + ((size_t)zo * NH_ + h) * N_ * D_ +
                   (size_t)half * NHALF_ * D_;
  const bf16* vz = vhf + ((size_t)zo * NH_ + h) * D_ * N_ +
                   (size_t)half * (NHALF_ / 32) * 1024;

  const int lane = tid & 63;
  const int w    = tid >> 6;
  const int ml   = lane & 15;
  const int q4   = lane >> 4;           // quad 0..3
  const int Q4   = q4 * 4;
  const int Q8   = q4 * 8;

  // Q fragments (B-operand): strip s4 -> row m0 + w*64 + s4*16 + ml
  sx8 qf[4];
  #pragma unroll
  for (int s4 = 0; s4 < 4; ++s4)
    qf[s4] = *(const sx8*)(qz + (size_t)(m0 + w * 64 + s4 * 16 + ml) * D_ + Q8);

  sx8 onesf;                            // bf16 1.0 row for the l-sum MFMA
  #pragma unroll
  for (int u = 0; u < 8; ++u) onesf[u] = (short)0x3F80;

  const fx4 z4 = {0.f, 0.f, 0.f, 0.f};
  fx4 acc[4][2];
  #pragma unroll
  for (int s4 = 0; s4 < 4; ++s4) { acc[s4][0] = z4; acc[s4][1] = z4; }
  fx4 lacc[4] = {z4, z4, z4, z4};

  // Direct-global fragment bases (lane-constant) — R15 addressing:
  //   K frag t of tile n0: kz + (n0 + t*16 + ml)*32 + Q8    (16 rows x 64B = 1KB)
  //   V frag [dt][c]:      vz + ((n0>>5)+c)*1024 + dt*512 + ml*32 + Q8
  const bf16* kbase = kz + (size_t)ml * D_ + Q8;
  const bf16* vbase = vz + (size_t)ml * 32 + Q8;

#define LDK(n0, kf)                                                          \
  {                                                                          \
    _Pragma("unroll") for (int t = 0; t < 4; ++t)                            \
        kf[t] = *(const sx8*)(kbase + (size_t)((n0) + t * 16) * D_);         \
  }
#define LDV(n0, vf)                                                          \
  {                                                                          \
    _Pragma("unroll") for (int dt = 0; dt < 2; ++dt)                         \
        _Pragma("unroll") for (int c = 0; c < 2; ++c)                        \
            vf[dt][c] = *(const sx8*)(vbase +                                \
                (size_t)(((n0) >> 5) + c) * 1024 + dt * 512);                \
  }

  sx8 kfA[4], kfB[4], vfA[2][2], vfB[2][2];
  LDK(0, kfA);
  LDV(0, vfA);

  #pragma unroll 1
  for (int n0 = 0; n0 < NHALF_; n0 += 128) {
    const int nn = n0 + 64;                       // always < NHALF_
    LDK(nn, kfB);
    LDV(nn, vfB);
    attn_tile(kfA, vfA, qf, onesf, acc, lacc);

    const int nn2 = (nn + 64 < NHALF_) ? nn + 64 : 0; // clamp: harmless re-read
    LDK(nn2, kfA);
    LDV(nn2, vfA);
    attn_tile(kfB, vfB, qf, onesf, acc, lacc);
  }
#undef LDK
#undef LDV

  // epilogue: store UNNORMALIZED partial O and this half's l (no divide).
  bf16* ath = attoT + (size_t)half * (2 * B_ * N_ * C_);
  #pragma unroll
  for (int s4 = 0; s4 < 4; ++s4) {
    int col = m0 + w * 64 + s4 * 16 + ml;
    if (q4 == 0)
      lws[(((size_t)half * 2 * B_ + z) * NH_ + h) * N_ + col] = lacc[s4][0];
    #pragma unroll
    for (int dt = 0; dt < 2; ++dt) {
      short tmp[4];
      #pragma unroll
      for (int r = 0; r < 4; ++r) tmp[r] = fbs(acc[s4][dt][r]);
      *(sx4*)(ath + ((size_t)z * N_ + col) * C_ + h * D_ + dt * 16 + Q4) =
          *(sx4*)tmp;
    }
  }
}

// ---------------------------------------------------------------------------
// Kernel 3: out_proj as MFMA GEMM. D = Wo * (A_s/l_s + A_f/l_f), residuals
// fused. R20: combines the split-K halves — A = A0+A1 (unnormalized bf16),
// l = l0+l1 (f32 from lws); per-(s,h,p) inverse staged in a small LDS table.
// grid (N_/64, 256/64, B_), block 256 (4 waves, each 32x32)
// ---------------------------------------------------------------------------
__global__ __launch_bounds__(256)
void out_proj_kernel(const bf16* __restrict__ wob, const bf16* __restrict__ attoT,
                     const float* __restrict__ lws,
                     const float* __restrict__ spatial,
                     const float* __restrict__ freq,
                     const float* __restrict__ bo, float* __restrict__ out) {
  const int tid = threadIdx.x;
  const int p0 = blockIdx.x * 64;
  const int o0 = blockIdx.y * 64;
  const int b  = blockIdx.z;

  const int lane = tid & 63, w = tid >> 6;
  const int ml = lane & 15, Q4 = (lane >> 4) * 4, Q8 = (lane >> 4) * 8;
  const int ow = (w >> 1) * 32, pw = (w & 1) * 32;

  __shared__ __align__(16) short asb[64 * 72];
  __shared__ __align__(16) short bsb[64 * 72];
  __shared__ float bo_s[64];
  __shared__ float linv[2][NH_][64];    // [s][h][p-local] = 1/(l0+l1)

  if (tid < 64) bo_s[tid] = 2.f * bo[o0 + tid];
  const size_t HSZ = (size_t)2 * B_ * N_ * C_;    // elems per half-slab
  for (int i = tid; i < 2 * NH_ * 64; i += 256) {
    int si = i >> 9, hi = (i >> 6) & (NH_ - 1), pi = i & 63;
    int zl = si * 2 + b;
    float l0 = lws[(((size_t)0 * 2 * B_ + zl) * NH_ + hi) * N_ + p0 + pi];
    float l1 = lws[(((size_t)1 * 2 * B_ + zl) * NH_ + hi) * N_ + p0 + pi];
    linv[si][hi][pi] = 1.f / (l0 + l1);
  }

  const bf16* a0s = attoT + (size_t)(0 + b) * N_ * C_;         // half0 s=0
  const bf16* a0f = attoT + (size_t)(2 + b) * N_ * C_;         // half0 s=1
  const bf16* a1s = attoT + HSZ + (size_t)(0 + b) * N_ * C_;   // half1 s=0
  const bf16* a1f = attoT + HSZ + (size_t)(2 + b) * N_ * C_;   // half1 s=1

  const fx4 z4 = {0.f, 0.f, 0.f, 0.f};
  fx4 acc[2][2];
  #pragma unroll
  for (int ot = 0; ot < 2; ++ot)
    #pragma unroll
    for (int pt = 0; pt < 2; ++pt) acc[ot][pt] = z4;

  for (int k0 = 0; k0 < 256; k0 += 64) {
    __syncthreads();
    #pragma unroll
    for (int i = 0; i < 2; ++i) {
      int j = tid + 256 * i;            // 0..511
      int r = j >> 3, cu = (j & 7) * 8;
      *(sx8*)&asb[r * 72 + cu] = *(const sx8*)&wob[(o0 + r) * 256 + k0 + cu];
      size_t aoff = (size_t)(p0 + r) * C_ + k0 + cu;
      sx8 v0s = *(const sx8*)(a0s + aoff);
      sx8 v1s = *(const sx8*)(a1s + aoff);
      sx8 v0f = *(const sx8*)(a0f + aoff);
      sx8 v1f = *(const sx8*)(a1f + aoff);
      int hidx = (k0 + cu) >> 5;        // 8-chunk never crosses a head
      float is = linv[0][hidx][r];
      float ifr = linv[1][hidx][r];
      short tmp[8];
      #pragma unroll
      for (int u = 0; u < 8; ++u)
        tmp[u] = fbs((sbf(v0s[u]) + sbf(v1s[u])) * is +
                     (sbf(v0f[u]) + sbf(v1f[u])) * ifr);
      *(sx8*)&bsb[r * 72 + cu] = *(sx8*)tmp;
    }
    __syncthreads();
    #pragma unroll
    for (int kk = 0; kk < 2; ++kk) {
      sx8 af[2], bfr[2];
      #pragma unroll
      for (int t = 0; t < 2; ++t)
        af[t] = *(sx8*)&asb[(ow + t * 16 + ml) * 72 + kk * 32 + Q8];
      #pragma unroll
      for (int t = 0; t < 2; ++t)
        bfr[t] = *(sx8*)&bsb[(pw + t * 16 + ml) * 72 + kk * 32 + Q8];
      #pragma unroll
      for (int ot = 0; ot < 2; ++ot)
        #pragma unroll
        for (int pt = 0; pt < 2; ++pt)
          acc[ot][pt] = __builtin_amdgcn_mfma_f32_16x16x32_bf16(
              af[ot], bfr[pt], acc[ot][pt], 0, 0, 0);
    }
  }

  #pragma unroll
  for (int ot = 0; ot < 2; ++ot)
    #pragma unroll
    for (int pt = 0; pt < 2; ++pt) {
      int p = p0 + pw + pt * 16 + ml;
      #pragma unroll
      for (int r = 0; r < 4; ++r) {
        int ol = ow + ot * 16 + Q4 + r;
        size_t off = ((size_t)b * C_ + o0 + ol) * N_ + p;
        out[off] = acc[ot][pt][r] + bo_s[ol] + spatial[off] + freq[off];
      }
    }
}

extern "C" void kernel_launch(void* const* d_in, const int* in_sizes, int n_in,
                              void* d_out, int out_size, void* d_ws, size_t ws_size,
                              hipStream_t stream) {
  const float* spatial = (const float*)d_in[0];
  const float* freq    = (const float*)d_in[1];
  const float* wq = (const float*)d_in[2];
  const float* bq = (const float*)d_in[3];
  const float* wk = (const float*)d_in[4];
  const float* bk = (const float*)d_in[5];
  const float* wv = (const float*)d_in[6];
  const float* bv = (const float*)d_in[7];
  const float* wo = (const float*)d_in[8];
  const float* bo = (const float*)d_in[9];
  float* out = (float*)d_out;

  // workspace layout (bf16 elements)
  const size_t SZ = (size_t)2 * B_ * N_ * C_;   // 4.19M elems = 8.4 MB
  bf16* xb    = (bf16*)d_ws;                    // [z][p][c]
  bf16* qhf   = xb + SZ;                        // [z][h][n][d]
  bf16* khf   = qhf + SZ;                       // [z][h][n][d]
  bf16* vhf   = khf + SZ;                       // [z][h] frag-blocked
  bf16* attoT = vhf + SZ;                       // [2 halves][z][p][c]
  bf16* wb    = attoT + 2 * SZ;                 // [768][256]
  bf16* wob   = wb + 768 * 256;                 // [256][256]
  float* lws  = (float*)(wob + 256 * 256);      // [2][z][h][n] f32 (1 MB)

  convert_kernel<<<dim3(N_ / 64, C_ / 64, 5), 256, 0, stream>>>(
      spatial, freq, wq, wk, wv, wo, xb, wb, wob);
  qkv_gemm_kernel<<<dim3(N_ / 128, 768 / 128, 2 * B_), 256, 0, stream>>>(
      wb, xb, bq, bk, bv, qhf, khf, vhf);
  attn_kernel<<<dim3(N_ / 256, NH_, 2 * B_ * 2), 256, 0, stream>>>(
      qhf, khf, vhf, attoT, lws);
  out_proj_kernel<<<dim3(N_ / 64, C_ / 64, B_), 256, 0, stream>>>(
      wob, attoT, lws, spatial, freq, bo, out);
}

// Round 7
// 189.230 us; speedup vs baseline: 2.5228x; 2.5228x over previous
//
#include <hip/hip_runtime.h>
#include <hip/hip_bf16.h>

#define B_ 2
#define C_ 256
#define NH_ 8
#define D_ 32
#define N_ 4096
#define SCALE_ 0.17677669529663689f
// SCALE * log2(e): folded into Q so softmax is a bare v_exp_f32 per score
#define QSC_ 0.25505277f

typedef __hip_bfloat16 bf16;
typedef __attribute__((ext_vector_type(8))) short sx8;   // 8 bf16 = one MFMA A/B frag
typedef __attribute__((ext_vector_type(4))) short sx4;
typedef __attribute__((ext_vector_type(4))) float fx4;   // MFMA C/D frag
typedef __attribute__((ext_vector_type(4))) int ix4;

__device__ __forceinline__ float b2f(bf16 x) { return __bfloat162float(x); }
__device__ __forceinline__ bf16 f2b(float x) { return __float2bfloat16(x); }
__device__ __forceinline__ short fbs(float x) { bf16 h = __float2bfloat16(x); return *(short*)&h; }
__device__ __forceinline__ float sbf(short s) { bf16 h = *(bf16*)&s; return __bfloat162float(h); }

#if __has_builtin(__builtin_amdgcn_exp2f)
__device__ __forceinline__ float fexp2(float x) { return __builtin_amdgcn_exp2f(x); }
#else
__device__ __forceinline__ float fexp2(float x) { return exp2f(x); }
#endif

// pack two f32 -> one dword of two bf16 by TRUNCATION (1 VALU op via v_perm).
// P in (0,1]; l sums the same truncated values so normalization cancels bias.
__device__ __forceinline__ unsigned pkbf_tr(float x, float y) {
#if __has_builtin(__builtin_amdgcn_perm)
  return __builtin_amdgcn_perm(__builtin_bit_cast(unsigned, y),
                               __builtin_bit_cast(unsigned, x), 0x07060302u);
#else
  unsigned a = __builtin_bit_cast(unsigned, x) >> 16;
  unsigned b = __builtin_bit_cast(unsigned, y) & 0xFFFF0000u;
  return a | b;
#endif
}
// gfx950 MFMA-transpose swaps (VALU cross-lane, not DS pipe) — validated R10.
// VOLATILE on purpose (R17 lesson: removing the fences lets the scheduler
// sink prefetch loads and destroy the software pipeline).
__device__ __forceinline__ void pl32swap(unsigned &a, unsigned &b) {
  asm volatile("v_permlane32_swap_b32 %0, %1" : "+v"(a), "+v"(b));
}
__device__ __forceinline__ void pl16swap(unsigned &a, unsigned &b) {
  asm volatile("v_permlane16_swap_b32 %0, %1" : "+v"(a), "+v"(b));
}

// ---------------------------------------------------------------------------
// Prep (merged): z<4 -> x transpose+convert to xb[z][p][c];
//                z==4 -> weights -> bf16 (wb stacked [wq;wk;wv], wob).
// grid (N_/64, C_/64, 5), block 256
// ---------------------------------------------------------------------------
__global__ __launch_bounds__(256)
void convert_kernel(const float* __restrict__ spatial,
                    const float* __restrict__ freq,
                    const float* __restrict__ wq, const float* __restrict__ wk,
                    const float* __restrict__ wv, const float* __restrict__ wo,
                    bf16* __restrict__ xb, bf16* __restrict__ wb,
                    bf16* __restrict__ wob) {
  const int tid = threadIdx.x;
  if (blockIdx.z == 4) {
    int base = (blockIdx.y * 64 + blockIdx.x) * 256 + tid;   // 0..65535
    #pragma unroll
    for (int i = 0; i < 4; ++i) {
      int idx = base + i * 65536;                            // 0..262143
      if (idx < 196608) {
        const float* src = (idx < 65536) ? wq : (idx < 131072) ? wk : wv;
        wb[idx] = f2b(src[idx & 65535]);
      } else {
        wob[idx - 196608] = f2b(wo[idx - 196608]);
      }
    }
    return;
  }

  const int p0 = blockIdx.x * 64;
  const int c0 = blockIdx.y * 64;
  const int z  = blockIdx.z;            // s*B_ + b
  const int s = z >> 1, b = z & 1;
  const float* x = (s == 0) ? spatial : freq;

  __shared__ float ls[64][65];

  const int pp = tid & 63, cb = tid >> 6;
  #pragma unroll
  for (int i = 0; i < 16; ++i) {
    int c = cb + 4 * i;
    ls[c][pp] = x[(size_t)(b * C_ + c0 + c) * N_ + p0 + pp];
  }
  __syncthreads();

  #pragma unroll
  for (int i = 0; i < 2; ++i) {
    int j = tid + 256 * i;              // 0..511
    int p = j >> 3, ck = (j & 7) * 8;
    short tmp[8];
    #pragma unroll
    for (int u = 0; u < 8; ++u) tmp[u] = fbs(ls[ck + u][p]);
    *(sx8*)(xb + ((size_t)z * N_ + p0 + p) * C_ + c0 + ck) = *(sx8*)tmp;
  }
}

// ---------------------------------------------------------------------------
// Kernel 1: QKV projection as MFMA GEMM. D = W (768x256) * x (256x4096) per z.
//   qhf/khf: per-head pos-major [z][h][n][d32]   (Q pre-scaled by QSC_)
//   vhf:     frag-blocked [z][h][n>>5][d>>4][d&15][n&31]
// R21: V-epilogue now stores via LDS transpose -> coalesced 16-B stores
// (old path: 64 scalar 2-B global stores/thread at 64-B stride = partial-
// line write amplification). Staging LDS is reused for the transpose.
// grid (N_/128, 768/128, 2*B_), block 256 (4 waves, each 64x64)
// ---------------------------------------------------------------------------
__global__ __launch_bounds__(256)
void qkv_gemm_kernel(const bf16* __restrict__ wb, const bf16* __restrict__ xb,
                     const float* __restrict__ bq, const float* __restrict__ bk,
                     const float* __restrict__ bv,
                     bf16* __restrict__ qhf, bf16* __restrict__ khf,
                     bf16* __restrict__ vhf) {
  const int tid = threadIdx.x;
  const int p0 = blockIdx.x * 128;
  const int o0 = blockIdx.y * 128;
  const int z  = blockIdx.z;

  const int lane = tid & 63, w = tid >> 6;
  const int ml = lane & 15, Q4 = (lane >> 4) * 4, Q8 = (lane >> 4) * 8;
  const int ow = (w >> 1) * 64, pw = (w & 1) * 64;

  __shared__ __align__(16) short smem[2 * 128 * 72];   // asb | bsb, reused by V-epi
  short* asb = smem;
  short* bsb = smem + 128 * 72;
  __shared__ float bias_s[128];

  if (tid < 128) {
    int o = o0 + tid;
    bias_s[tid] = (o < 256) ? bq[o] : (o < 512) ? bk[o - 256] : bv[o - 512];
  }

  const fx4 z4 = {0.f, 0.f, 0.f, 0.f};
  fx4 acc[4][4];
  #pragma unroll
  for (int ot = 0; ot < 4; ++ot)
    #pragma unroll
    for (int pt = 0; pt < 4; ++pt) acc[ot][pt] = z4;

  const int sr = tid >> 1, scu = (tid & 1) * 32;
  for (int k0 = 0; k0 < 256; k0 += 64) {
    __syncthreads();
    #pragma unroll
    for (int u = 0; u < 4; ++u) {
      *(sx8*)&asb[sr * 72 + scu + u * 8] =
          *(const sx8*)&wb[(o0 + sr) * 256 + k0 + scu + u * 8];
      *(sx8*)&bsb[sr * 72 + scu + u * 8] =
          *(const sx8*)(xb + ((size_t)z * N_ + p0 + sr) * C_ + k0 + scu + u * 8);
    }
    __syncthreads();
    #pragma unroll
    for (int kk = 0; kk < 2; ++kk) {
      sx8 af[4], bfr[4];
      #pragma unroll
      for (int t = 0; t < 4; ++t)
        af[t] = *(sx8*)&asb[(ow + t * 16 + ml) * 72 + kk * 32 + Q8];
      #pragma unroll
      for (int t = 0; t < 4; ++t)
        bfr[t] = *(sx8*)&bsb[(pw + t * 16 + ml) * 72 + kk * 32 + Q8];
      #pragma unroll
      for (int ot = 0; ot < 4; ++ot)
        #pragma unroll
        for (int pt = 0; pt < 4; ++pt)
          acc[ot][pt] = __builtin_amdgcn_mfma_f32_16x16x32_bf16(
              af[ot], bfr[pt], acc[ot][pt], 0, 0, 0);
    }
  }

  if (o0 < 512) {
    bf16* dst = (o0 < 256) ? qhf : khf;
    const int ob = (o0 < 256) ? o0 : o0 - 256;
    const float scl = (o0 < 256) ? QSC_ : 1.f;
    #pragma unroll
    for (int ot = 0; ot < 4; ++ot) {
      const int og = ob + ow + ot * 16 + Q4;    // global o, head = og>>5
      #pragma unroll
      for (int pt = 0; pt < 4; ++pt) {
        int p = p0 + pw + pt * 16 + ml;
        short tmp[4];
        #pragma unroll
        for (int r = 0; r < 4; ++r)
          tmp[r] = fbs((acc[ot][pt][r] + bias_s[ow + ot * 16 + Q4 + r]) * scl);
        *(sx4*)(dst + (((size_t)z * NH_ + (og >> 5)) * N_ + p) * D_ + (og & 31)) =
            *(sx4*)tmp;
      }
    }
  } else {
    // V: stage the 128x128 tile into LDS as bf16 [o][p] (pitch 136), then
    // each thread emits 8 coalesced sx8 stores along vhf's n&31 axis.
    __syncthreads();                    // k-loop LDS consumption complete
    #pragma unroll
    for (int ot = 0; ot < 4; ++ot)
      #pragma unroll
      for (int pt = 0; pt < 4; ++pt) {
        int pl = pw + pt * 16 + ml;
        #pragma unroll
        for (int r = 0; r < 4; ++r) {
          int lo = ow + ot * 16 + Q4 + r;       // local o in [0,128)
          smem[lo * 136 + pl] = fbs(acc[ot][pt][r] + bias_s[lo]);
        }
      }
    __syncthreads();
    const int rho0 = o0 - 512;                  // 0 or 128
    #pragma unroll
    for (int i = 0; i < 8; ++i) {
      int j = tid + 256 * i;                    // 0..2047
      int lo = j >> 4, pg = j & 15;
      int rho = rho0 + lo;                      // 0..255
      int h = rho >> 5, d = rho & 31;
      int p = p0 + pg * 8;                      // global p
      size_t basev = ((size_t)z * NH_ + h) * D_ * N_;
      sx8 v = *(sx8*)&smem[lo * 136 + pg * 8];
      *(sx8*)(vhf + basev + (size_t)(p >> 5) * 1024 + (d >> 4) * 512 +
              (d & 15) * 32 + (p & 31)) = v;
    }
  }
}

// ---------------------------------------------------------------------------
// Kernel 2: MFMA flash attention — R15 anchor, verbatim (98.4us, best).
// Zero LDS / zero barriers; K/V MFMA A-frags load DIRECTLY from global
// (layouts pre-arranged by kernel 1) as coalesced 1KB wave transactions;
// register double-buffer prefetch; setprio + volatile-swap fences pin the
// pipeline. Post-R16..R20 conclusion: elapsed == MFMA + VALU + ~38% stall
// at 2 waves/SIMD; more waves (R16/R20), scheduler freedom (R17), manual
// pipelining (R18), cheaper exp (R19) all regressed — this is the floor
// for this structure.
// grid (N_/256, NH_, 4), block 256 (4 independent waves, 64 q each)
// ---------------------------------------------------------------------------
__device__ __forceinline__ void attn_tile(const sx8 kf[4], const sx8 vf[2][2],
                                          const sx8 qf[4], sx8 onesf,
                                          fx4 acc[4][2], fx4 lacc[4]) {
  const fx4 z4 = {0.f, 0.f, 0.f, 0.f};
  #pragma unroll
  for (int s4 = 0; s4 < 4; ++s4) {
    fx4 st[4];
    __builtin_amdgcn_s_setprio(1);
    #pragma unroll
    for (int t = 0; t < 4; ++t)
      st[t] = __builtin_amdgcn_mfma_f32_16x16x32_bf16(kf[t], qf[s4], z4, 0, 0, 0);
    __builtin_amdgcn_s_setprio(0);

    // exp + truncate-pack each tile's 4 values into 2 dwords
    unsigned T[4][2];
    #pragma unroll
    for (int t = 0; t < 4; ++t) {
      float e0 = fexp2(st[t][0]), e1 = fexp2(st[t][1]);
      float e2 = fexp2(st[t][2]), e3 = fexp2(st[t][3]);
      T[t][0] = pkbf_tr(e0, e1);
      T[t][1] = pkbf_tr(e2, e3);
    }
    // in-register C-layout -> B-operand transform (validated R10)
    pl32swap(T[0][0], T[1][0]); pl16swap(T[0][0], T[1][0]);
    pl32swap(T[0][1], T[1][1]); pl16swap(T[0][1], T[1][1]);
    pl32swap(T[2][0], T[3][0]); pl16swap(T[2][0], T[3][0]);
    pl32swap(T[2][1], T[3][1]); pl16swap(T[2][1], T[3][1]);
    ix4 p0 = {(int)T[0][0], (int)T[0][1], (int)T[1][0], (int)T[1][1]};
    ix4 p1 = {(int)T[2][0], (int)T[2][1], (int)T[3][0], (int)T[3][1]};
    sx8 pf0 = *(sx8*)&p0;
    sx8 pf1 = *(sx8*)&p1;

    __builtin_amdgcn_s_setprio(1);
    lacc[s4] = __builtin_amdgcn_mfma_f32_16x16x32_bf16(onesf, pf0, lacc[s4], 0, 0, 0);
    lacc[s4] = __builtin_amdgcn_mfma_f32_16x16x32_bf16(onesf, pf1, lacc[s4], 0, 0, 0);
    #pragma unroll
    for (int dt = 0; dt < 2; ++dt) {
      fx4 a = acc[s4][dt];
      a = __builtin_amdgcn_mfma_f32_16x16x32_bf16(vf[dt][0], pf0, a, 0, 0, 0);
      a = __builtin_amdgcn_mfma_f32_16x16x32_bf16(vf[dt][1], pf1, a, 0, 0, 0);
      acc[s4][dt] = a;
    }
    __builtin_amdgcn_s_setprio(0);
  }
}

__global__ __launch_bounds__(256, 2)
void attn_kernel(const bf16* __restrict__ qhf, const bf16* __restrict__ khf,
                 const bf16* __restrict__ vhf, bf16* __restrict__ attoT) {
  const int tid  = threadIdx.x;
  const int m0   = blockIdx.x * 256;
  const int h    = blockIdx.y;
  const int z    = blockIdx.z;          // s*B_ + b
  const int s = z >> 1, b = z & 1;
  const int zo = ((1 - s) << 1) | b;    // kv source

  const bf16* qz = qhf + ((size_t)z  * NH_ + h) * N_ * D_;
  const bf16* kz = khf + ((size_t)zo * NH_ + h) * N_ * D_;
  const bf16* vz = vhf + ((size_t)zo * NH_ + h) * D_ * N_;

  const int lane = tid & 63;
  const int w    = tid >> 6;
  const int ml   = lane & 15;
  const int q4   = lane >> 4;           // quad 0..3
  const int Q4   = q4 * 4;
  const int Q8   = q4 * 8;

  // Q fragments (B-operand): strip s4 -> row m0 + w*64 + s4*16 + ml
  sx8 qf[4];
  #pragma unroll
  for (int s4 = 0; s4 < 4; ++s4)
    qf[s4] = *(const sx8*)(qz + (size_t)(m0 + w * 64 + s4 * 16 + ml) * D_ + Q8);

  sx8 onesf;                            // bf16 1.0 row for the l-sum MFMA
  #pragma unroll
  for (int u = 0; u < 8; ++u) onesf[u] = (short)0x3F80;

  const fx4 z4 = {0.f, 0.f, 0.f, 0.f};
  fx4 acc[4][2];
  #pragma unroll
  for (int s4 = 0; s4 < 4; ++s4) { acc[s4][0] = z4; acc[s4][1] = z4; }
  fx4 lacc[4] = {z4, z4, z4, z4};

  // Direct-global fragment bases (lane-constant):
  //   K frag t of tile n0: kz + (n0 + t*16 + ml)*32 + Q8    (16 rows x 64B = 1KB)
  //   V frag [dt][c]:      vz + ((n0>>5)+c)*1024 + dt*512 + ml*32 + Q8
  const bf16* kbase = kz + (size_t)ml * D_ + Q8;
  const bf16* vbase = vz + (size_t)ml * 32 + Q8;

#define LDK(n0, kf)                                                          \
  {                                                                          \
    _Pragma("unroll") for (int t = 0; t < 4; ++t)                            \
        kf[t] = *(const sx8*)(kbase + (size_t)((n0) + t * 16) * D_);         \
  }
#define LDV(n0, vf)                                                          \
  {                                                                          \
    _Pragma("unroll") for (int dt = 0; dt < 2; ++dt)                         \
        _Pragma("unroll") for (int c = 0; c < 2; ++c)                        \
            vf[dt][c] = *(const sx8*)(vbase +                                \
                (size_t)(((n0) >> 5) + c) * 1024 + dt * 512);                \
  }

  sx8 kfA[4], kfB[4], vfA[2][2], vfB[2][2];
  LDK(0, kfA);
  LDV(0, vfA);

  #pragma unroll 1
  for (int n0 = 0; n0 < N_; n0 += 128) {
    const int nn = n0 + 64;                       // always < N_
    LDK(nn, kfB);
    LDV(nn, vfB);
    attn_tile(kfA, vfA, qf, onesf, acc, lacc);

    const int nn2 = (nn + 64 < N_) ? nn + 64 : 0; // clamp: harmless re-read
    LDK(nn2, kfA);
    LDV(nn2, vfA);
    attn_tile(kfB, vfB, qf, onesf, acc, lacc);
  }
#undef LDK
#undef LDV

  // epilogue: l for this lane's query column is lacc[s4][0] (all rows equal)
  #pragma unroll
  for (int s4 = 0; s4 < 4; ++s4) {
    float inv = 1.f / lacc[s4][0];
    int col = m0 + w * 64 + s4 * 16 + ml;
    #pragma unroll
    for (int dt = 0; dt < 2; ++dt) {
      short tmp[4];
      #pragma unroll
      for (int r = 0; r < 4; ++r) tmp[r] = fbs(acc[s4][dt][r] * inv);
      *(sx4*)(attoT + ((size_t)z * N_ + col) * C_ + h * D_ + dt * 16 + Q4) =
          *(sx4*)tmp;
    }
  }
}

// ---------------------------------------------------------------------------
// Kernel 3: out_proj as MFMA GEMM. D = Wo * (attS + attF), residuals fused.
// p-tile 64 -> grid 512 blocks = 2/CU (was 256 = 1/CU, occupancy-starved).
// grid (N_/64, 256/64, B_), block 256 (4 waves, each 32x32)
// ---------------------------------------------------------------------------
__global__ __launch_bounds__(256)
void out_proj_kernel(const bf16* __restrict__ wob, const bf16* __restrict__ attoT,
                     const float* __restrict__ spatial,
                     const float* __restrict__ freq,
                     const float* __restrict__ bo, float* __restrict__ out) {
  const int tid = threadIdx.x;
  const int p0 = blockIdx.x * 64;
  const int o0 = blockIdx.y * 64;
  const int b  = blockIdx.z;

  const int lane = tid & 63, w = tid >> 6;
  const int ml = lane & 15, Q4 = (lane >> 4) * 4, Q8 = (lane >> 4) * 8;
  const int ow = (w >> 1) * 32, pw = (w & 1) * 32;

  __shared__ __align__(16) short asb[64 * 72];
  __shared__ __align__(16) short bsb[64 * 72];
  __shared__ float bo_s[64];

  if (tid < 64) bo_s[tid] = 2.f * bo[o0 + tid];

  const bf16* at0 = attoT + (size_t)(0 + b) * N_ * C_;   // s=0 slice
  const bf16* at1 = attoT + (size_t)(2 + b) * N_ * C_;   // s=1 slice

  const fx4 z4 = {0.f, 0.f, 0.f, 0.f};
  fx4 acc[2][2];
  #pragma unroll
  for (int ot = 0; ot < 2; ++ot)
    #pragma unroll
    for (int pt = 0; pt < 2; ++pt) acc[ot][pt] = z4;

  for (int k0 = 0; k0 < 256; k0 += 64) {
    __syncthreads();
    #pragma unroll
    for (int i = 0; i < 2; ++i) {
      int j = tid + 256 * i;            // 0..511
      int r = j >> 3, cu = (j & 7) * 8;
      *(sx8*)&asb[r * 72 + cu] = *(const sx8*)&wob[(o0 + r) * 256 + k0 + cu];
      sx8 va = *(const sx8*)(at0 + (size_t)(p0 + r) * C_ + k0 + cu);
      sx8 vb2 = *(const sx8*)(at1 + (size_t)(p0 + r) * C_ + k0 + cu);
      short tmp[8];
      #pragma unroll
      for (int u = 0; u < 8; ++u) tmp[u] = fbs(sbf(va[u]) + sbf(vb2[u]));
      *(sx8*)&bsb[r * 72 + cu] = *(sx8*)tmp;
    }
    __syncthreads();
    #pragma unroll
    for (int kk = 0; kk < 2; ++kk) {
      sx8 af[2], bfr[2];
      #pragma unroll
      for (int t = 0; t < 2; ++t)
        af[t] = *(sx8*)&asb[(ow + t * 16 + ml) * 72 + kk * 32 + Q8];
      #pragma unroll
      for (int t = 0; t < 2; ++t)
        bfr[t] = *(sx8*)&bsb[(pw + t * 16 + ml) * 72 + kk * 32 + Q8];
      #pragma unroll
      for (int ot = 0; ot < 2; ++ot)
        #pragma unroll
        for (int pt = 0; pt < 2; ++pt)
          acc[ot][pt] = __builtin_amdgcn_mfma_f32_16x16x32_bf16(
              af[ot], bfr[pt], acc[ot][pt], 0, 0, 0);
    }
  }

  #pragma unroll
  for (int ot = 0; ot < 2; ++ot)
    #pragma unroll
    for (int pt = 0; pt < 2; ++pt) {
      int p = p0 + pw + pt * 16 + ml;
      #pragma unroll
      for (int r = 0; r < 4; ++r) {
        int ol = ow + ot * 16 + Q4 + r;
        size_t off = ((size_t)b * C_ + o0 + ol) * N_ + p;
        out[off] = acc[ot][pt][r] + bo_s[ol] + spatial[off] + freq[off];
      }
    }
}

extern "C" void kernel_launch(void* const* d_in, const int* in_sizes, int n_in,
                              void* d_out, int out_size, void* d_ws, size_t ws_size,
                              hipStream_t stream) {
  const float* spatial = (const float*)d_in[0];
  const float* freq    = (const float*)d_in[1];
  const float* wq = (const float*)d_in[2];
  const float* bq = (const float*)d_in[3];
  const float* wk = (const float*)d_in[4];
  const float* bk = (const float*)d_in[5];
  const float* wv = (const float*)d_in[6];
  const float* bv = (const float*)d_in[7];
  const float* wo = (const float*)d_in[8];
  const float* bo = (const float*)d_in[9];
  float* out = (float*)d_out;

  // workspace layout (bf16 elements)
  const size_t SZ = (size_t)2 * B_ * N_ * C_;   // 4.19M elems = 8.4 MB
  bf16* xb    = (bf16*)d_ws;                    // [z][p][c]
  bf16* qhf   = xb + SZ;                        // [z][h][n][d]
  bf16* khf   = qhf + SZ;                       // [z][h][n][d]
  bf16* vhf   = khf + SZ;                       // [z][h] frag-blocked
  bf16* attoT = vhf + SZ;                       // [z][p][c]
  bf16* wb    = attoT + SZ;                     // [768][256]
  bf16* wob   = wb + 768 * 256;                 // [256][256]

  convert_kernel<<<dim3(N_ / 64, C_ / 64, 5), 256, 0, stream>>>(
      spatial, freq, wq, wk, wv, wo, xb, wb, wob);
  qkv_gemm_kernel<<<dim3(N_ / 128, 768 / 128, 2 * B_), 256, 0, stream>>>(
      wb, xb, bq, bk, bv, qhf, khf, vhf);
  attn_kernel<<<dim3(N_ / 256, NH_, 2 * B_), 256, 0, stream>>>(
      qhf, khf, vhf, attoT);
  out_proj_kernel<<<dim3(N_ / 64, C_ / 64, B_), 256, 0, stream>>>(
      wob, attoT, spatial, freq, bo, out);
}